// Round 12
// baseline (82.815 us; speedup 1.0000x reference)
//
#include <hip/hip_runtime.h>
#include <cstddef>

// B=256 batches, N=256 nodes, F=128 features.
// 5-kernel full-occupancy pipeline:
//   k_packW2   : W1/W2 -> MFMA A-fragment order
//   k_deg_conv : adj -> Abf (bf16, diag=1) + dinv          (R3-verified)
//   k_layer1   : grid 512 (2 blocks/batch): T1 (full, LDS) + agg n-half -> H1
//   k_layer2   : grid 512: T2 (full, LDS) + agg n-half + partial pool -> pp
//   k_pool     : combine partials + readout -> out
// k_layer1/2 use 65/73 KB LDS + __launch_bounds__(512,4) => 2 blocks/CU,
// 16 waves/CU (vs 8 in the monolithic design).

typedef __attribute__((ext_vector_type(8))) short short8;
typedef __attribute__((ext_vector_type(4))) float f32x4;

static __device__ __forceinline__ unsigned short f2bf(float f) {
  unsigned int u = __float_as_uint(f);
  u += 0x7FFFu + ((u >> 16) & 1u);   // round-nearest-even to bf16
  return (unsigned short)(u >> 16);
}

static __device__ __forceinline__ f32x4 mfma16(short8 a, short8 b, f32x4 c) {
  return __builtin_amdgcn_mfma_f32_16x16x32_bf16(a, b, c, 0, 0, 0);
}

// LDS byte addressing with XOR swizzle (T: [f][256] bf16).
static __device__ __forceinline__ int byteT(int f, int k) {
  return ((f << 9) + (k << 1)) ^ ((f & 7) << 4);
}

// ---------------- kernel: degree + bf16 convert (diag := 1) ------------------
__global__ __launch_bounds__(256) void k_deg_conv(
    const float* __restrict__ adj, unsigned short* __restrict__ Abf,
    float* __restrict__ dinv) {
  const int wid = (blockIdx.x << 2) + (threadIdx.x >> 6);  // wave id 0..8191
  const int t = threadIdx.x & 63;
  const int row0 = wid << 3;                               // 8 rows per wave
  const size_t base0 = (size_t)row0 * 256;
  const int c0 = 4 * t;

  float4 v[8];
  #pragma unroll
  for (int r = 0; r < 8; ++r)
    v[r] = *reinterpret_cast<const float4*>(adj + base0 + (size_t)r * 256 + c0);

  float s[8];
  #pragma unroll
  for (int r = 0; r < 8; ++r) {
    const int n = (row0 + r) & 255;
    v[r].x = (n == c0 + 0) ? 1.0f : v[r].x;
    v[r].y = (n == c0 + 1) ? 1.0f : v[r].y;
    v[r].z = (n == c0 + 2) ? 1.0f : v[r].z;
    v[r].w = (n == c0 + 3) ? 1.0f : v[r].w;
    s[r] = (v[r].x + v[r].y) + (v[r].z + v[r].w);
  }
  #pragma unroll
  for (int off = 32; off >= 1; off >>= 1) {
    #pragma unroll
    for (int r = 0; r < 8; ++r) s[r] += __shfl_xor(s[r], off);
  }

  float sel = s[0];
  #pragma unroll
  for (int r = 1; r < 8; ++r) sel = (t == r) ? s[r] : sel;
  if (t < 8) dinv[row0 + t] = rsqrtf(fmaxf(sel, 1.0f));

  #pragma unroll
  for (int r = 0; r < 8; ++r) {
    ushort4 o;
    o.x = f2bf(v[r].x); o.y = f2bf(v[r].y);
    o.z = f2bf(v[r].z); o.w = f2bf(v[r].w);
    *reinterpret_cast<ushort4*>(Abf + base0 + (size_t)r * 256 + c0) = o;
  }
}

// ---------------- pack W1 and W2 (128x128 f32) into MFMA A-fragment order ----
__global__ __launch_bounds__(64) void k_packW2(
    const float* __restrict__ W1, const float* __restrict__ W2,
    unsigned short* __restrict__ P1, unsigned short* __restrict__ P2) {
  const float* W = (blockIdx.x < 32) ? W1 : W2;
  unsigned short* P = (blockIdx.x < 32) ? P1 : P2;
  const int bb = blockIdx.x & 31;
  const int ks = bb >> 3;
  const int r = bb & 7;
  const int l = threadIdx.x;
  const int col = r * 16 + (l & 15);
  const int k0 = ks * 32 + ((l >> 4) << 3);
  short8 frag;
  #pragma unroll
  for (int j = 0; j < 8; ++j)
    frag[j] = (short)f2bf(W[(size_t)(k0 + j) * 128 + col]);
  *reinterpret_cast<short8*>(P + ((size_t)((ks * 8 + r) * 64 + l)) * 8) = frag;
}

// ---------------- layer 1: T1 = dinv*(x@W1) (full, LDS); agg n-half -> H1 ---
__global__ __launch_bounds__(512, 4) void k_layer1(
    const unsigned short* __restrict__ Abf, const float* __restrict__ x,
    const unsigned short* __restrict__ W1p, const float* __restrict__ b1,
    const float* __restrict__ dinv, unsigned short* __restrict__ H1) {
  __shared__ __align__(16) char bufT[65536];   // T1 [f][256] bf16 swizzled
  __shared__ float dinv_s[256];

  const int b = blockIdx.x >> 1;
  const int half = blockIdx.x & 1;
  const int tid = threadIdx.x;
  const int w = tid >> 6;
  const int l = tid & 63;
  const int l15 = l & 15;
  const int khalf = (l >> 4) << 3;
  const int qbase = (l >> 4) << 2;
  const int m = (w << 4) + l15;
  const unsigned short* Ab = Abf + ((size_t)b << 16);

  if (tid < 256) dinv_s[tid] = dinv[(b << 8) + tid];
  __syncthreads();

  // ---- P1: full T1[f][m'] = dinv[m']*(x@W1)[m'][f] -> bufT (swizzled) ----
  {
    const short8* Wf = reinterpret_cast<const short8*>(W1p);
    #pragma unroll
    for (int p = 0; p < 2; ++p) {
      const int mp = (p << 7) + m;
      const float* xr = x + ((((size_t)b << 8) + mp) << 7);
      float4 xc[8];
      #pragma unroll
      for (int ks = 0; ks < 4; ++ks) {
        xc[2 * ks]     = *reinterpret_cast<const float4*>(xr + (ks << 5) + khalf);
        xc[2 * ks + 1] = *reinterpret_cast<const float4*>(xr + (ks << 5) + khalf + 4);
      }
      f32x4 acc[8];
      #pragma unroll
      for (int r = 0; r < 8; ++r) acc[r] = (f32x4)(0.0f);
      #pragma unroll
      for (int ks = 0; ks < 4; ++ks) {
        const float4 u = xc[2 * ks], vv = xc[2 * ks + 1];
        short8 bf;
        bf[0] = (short)f2bf(u.x);  bf[1] = (short)f2bf(u.y);
        bf[2] = (short)f2bf(u.z);  bf[3] = (short)f2bf(u.w);
        bf[4] = (short)f2bf(vv.x); bf[5] = (short)f2bf(vv.y);
        bf[6] = (short)f2bf(vv.z); bf[7] = (short)f2bf(vv.w);
        #pragma unroll
        for (int r = 0; r < 8; ++r)
          acc[r] = mfma16(Wf[((ks << 3) + r) * 64 + l], bf, acc[r]);
      }
      const float sc = dinv_s[mp];
      #pragma unroll
      for (int r = 0; r < 8; ++r)
        #pragma unroll
        for (int q = 0; q < 4; ++q)
          *reinterpret_cast<unsigned short*>(bufT + byteT((r << 4) + qbase + q, mp)) =
              f2bf(acc[r][q] * sc);
    }
  }
  __syncthreads();

  // ---- P2: H1 rows [half*128 + w*16, +16) = dinv[n]*(A'@T1)+b1 -> global ----
  {
    float bs[8];
    #pragma unroll
    for (int c = 0; c < 8; ++c) bs[c] = b1[(c << 4) + l15];
    const int nb = (half << 7) + (w << 4);
    short8 af[8];
    #pragma unroll
    for (int ks = 0; ks < 8; ++ks)
      af[ks] = *reinterpret_cast<const short8*>(
          Ab + (size_t)(nb + l15) * 256 + (ks << 5) + khalf);
    f32x4 acc[8];
    #pragma unroll
    for (int c = 0; c < 8; ++c) acc[c] = (f32x4)(0.0f);
    #pragma unroll
    for (int ks = 0; ks < 8; ++ks) {
      const int k0 = (ks << 5) + khalf;
      #pragma unroll
      for (int c = 0; c < 8; ++c) {
        short8 bf = *reinterpret_cast<const short8*>(bufT + byteT((c << 4) + l15, k0));
        acc[c] = mfma16(af[ks], bf, acc[c]);
      }
    }
    #pragma unroll
    for (int q = 0; q < 4; ++q) {
      const int n = nb + qbase + q;
      const float dv = dinv_s[n];
      #pragma unroll
      for (int c = 0; c < 8; ++c)
        H1[(((size_t)(b << 8) + n) << 7) + (c << 4) + l15] =
            f2bf(acc[c][q] * dv + bs[c]);
    }
  }
}

// ---------------- layer 2: T2 (full, LDS) + agg n-half + partial pool -------
__global__ __launch_bounds__(512, 4) void k_layer2(
    const unsigned short* __restrict__ Abf, const unsigned short* __restrict__ H1,
    const unsigned short* __restrict__ W2p, const float* __restrict__ b2,
    const float* __restrict__ dinv, float* __restrict__ pp) {
  __shared__ __align__(16) char bufT[65536];   // T2 [f][256] bf16 swizzled
  __shared__ float lds_sum[8][128];
  __shared__ float lds_max[8][128];
  __shared__ float dinv_s[256];

  const int b = blockIdx.x >> 1;
  const int half = blockIdx.x & 1;
  const int tid = threadIdx.x;
  const int w = tid >> 6;
  const int l = tid & 63;
  const int l15 = l & 15;
  const int khalf = (l >> 4) << 3;
  const int qbase = (l >> 4) << 2;
  const int m = (w << 4) + l15;
  const unsigned short* Ab = Abf + ((size_t)b << 16);
  const unsigned short* Hb = H1 + ((size_t)b << 15);

  if (tid < 256) dinv_s[tid] = dinv[(b << 8) + tid];
  __syncthreads();

  // ---- P3: full T2[f][m'] = dinv[m']*(H1@W2)[m'][f] -> bufT (swizzled) ----
  {
    const short8* Wf = reinterpret_cast<const short8*>(W2p);
    #pragma unroll
    for (int p = 0; p < 2; ++p) {
      const int mp = (p << 7) + m;
      f32x4 acc[8];
      #pragma unroll
      for (int r = 0; r < 8; ++r) acc[r] = (f32x4)(0.0f);
      #pragma unroll
      for (int ks = 0; ks < 4; ++ks) {
        const int kk = (ks << 5) + khalf;
        short8 hf = *reinterpret_cast<const short8*>(Hb + ((size_t)mp << 7) + kk);
        #pragma unroll
        for (int r = 0; r < 8; ++r)
          acc[r] = mfma16(Wf[((ks << 3) + r) * 64 + l], hf, acc[r]);
      }
      const float sc = dinv_s[mp];
      #pragma unroll
      for (int r = 0; r < 8; ++r)
        #pragma unroll
        for (int q = 0; q < 4; ++q)
          *reinterpret_cast<unsigned short*>(bufT + byteT((r << 4) + qbase + q, mp)) =
              f2bf(acc[r][q] * sc);
    }
  }
  __syncthreads();

  // ---- P4: H2 rows [half*128 + w*16, +16) + partial mean/max pool ----
  {
    float bs[8], psum[8], pmax[8];
    #pragma unroll
    for (int c = 0; c < 8; ++c) {
      bs[c] = b2[(c << 4) + l15];
      psum[c] = 0.0f; pmax[c] = -1e30f;
    }
    const int nb = (half << 7) + (w << 4);
    short8 af[8];
    #pragma unroll
    for (int ks = 0; ks < 8; ++ks)
      af[ks] = *reinterpret_cast<const short8*>(
          Ab + (size_t)(nb + l15) * 256 + (ks << 5) + khalf);
    f32x4 acc[8];
    #pragma unroll
    for (int c = 0; c < 8; ++c) acc[c] = (f32x4)(0.0f);
    #pragma unroll
    for (int ks = 0; ks < 8; ++ks) {
      const int k0 = (ks << 5) + khalf;
      #pragma unroll
      for (int c = 0; c < 8; ++c) {
        short8 bf = *reinterpret_cast<const short8*>(bufT + byteT((c << 4) + l15, k0));
        acc[c] = mfma16(af[ks], bf, acc[c]);
      }
    }
    #pragma unroll
    for (int q = 0; q < 4; ++q) {
      const int n = nb + qbase + q;
      const float dv = dinv_s[n];
      #pragma unroll
      for (int c = 0; c < 8; ++c) {
        const float v = acc[c][q] * dv + bs[c];
        psum[c] += v;
        pmax[c] = fmaxf(pmax[c], v);
      }
    }
    // reduce across the 4 lane-groups sharing the same f (=c*16+l15)
    #pragma unroll
    for (int c = 0; c < 8; ++c) {
      psum[c] += __shfl_xor(psum[c], 16);
      pmax[c] = fmaxf(pmax[c], __shfl_xor(pmax[c], 16));
      psum[c] += __shfl_xor(psum[c], 32);
      pmax[c] = fmaxf(pmax[c], __shfl_xor(pmax[c], 32));
    }
    if (l < 16) {
      #pragma unroll
      for (int c = 0; c < 8; ++c) {
        lds_sum[w][(c << 4) + l] = psum[c];
        lds_max[w][(c << 4) + l] = pmax[c];
      }
    }
    __syncthreads();
    // pp layout: [block][ sum(128) | max(128) ]
    if (tid < 128) {
      float s = 0.0f;
      #pragma unroll
      for (int ww = 0; ww < 8; ++ww) s += lds_sum[ww][tid];
      pp[((size_t)blockIdx.x << 8) + tid] = s;
    } else if (tid < 256) {
      const int f = tid & 127;
      float mx = -1e30f;
      #pragma unroll
      for (int ww = 0; ww < 8; ++ww) mx = fmaxf(mx, lds_max[ww][f]);
      pp[((size_t)blockIdx.x << 8) + 128 + f] = mx;
    }
  }
}

// ---------------- pool combine + readout ------------------------------------
__global__ __launch_bounds__(256) void k_pool(
    const float* __restrict__ pp, const float* __restrict__ Wr,
    const float* __restrict__ br, float* __restrict__ out) {
  __shared__ float pooled[256];
  __shared__ float rp[256];

  const int b = blockIdx.x;
  const int tid = threadIdx.x;
  const float* p0 = pp + ((size_t)(b << 1) << 8);
  const float* p1 = p0 + 256;

  if (tid < 128) {
    pooled[tid] = (p0[tid] + p1[tid]) * (1.0f / 256.0f);
  } else {
    const int f = tid & 127;
    pooled[128 + f] = fmaxf(p0[128 + f], p1[128 + f]);
  }
  __syncthreads();

  {   // readout: 2 partial-dot slices of 128 each
    const int f = tid & 127, part = tid >> 7;
    const int base = part << 7;
    float o0 = 0.f, o1 = 0.f;
    #pragma unroll 4
    for (int i = 0; i < 128; i += 2) {
      o0 = fmaf(pooled[base + i],     Wr[(base + i) * 128 + f],     o0);
      o1 = fmaf(pooled[base + i + 1], Wr[(base + i + 1) * 128 + f], o1);
    }
    rp[(part << 7) + f] = o0 + o1;
  }
  __syncthreads();
  if (tid < 128)
    out[(b << 7) + tid] = rp[tid] + rp[128 + tid] + br[tid];
}

extern "C" void kernel_launch(void* const* d_in, const int* in_sizes, int n_in,
                              void* d_out, int out_size, void* d_ws, size_t ws_size,
                              hipStream_t stream) {
  const float* x   = (const float*)d_in[0];
  const float* adj = (const float*)d_in[1];
  const float* W1  = (const float*)d_in[2];
  const float* b1  = (const float*)d_in[3];
  const float* W2  = (const float*)d_in[4];
  const float* b2  = (const float*)d_in[5];
  const float* Wr  = (const float*)d_in[6];
  const float* br  = (const float*)d_in[7];
  float* out = (float*)d_out;

  char* ws = (char*)d_ws;
  unsigned short* Abf  = (unsigned short*)(ws);             // 33,554,432 B
  unsigned short* H1   = (unsigned short*)(ws + 33554432);  // 16,777,216 B
  float*          dinv = (float*)(ws + 50331648);           //    262,144 B
  float*          pp   = (float*)(ws + 50593792);           //    524,288 B
  unsigned short* W1p  = (unsigned short*)(ws + 51118080);  //     32,768 B
  unsigned short* W2p  = (unsigned short*)(ws + 51150848);  //     32,768 B

  k_packW2<<<64, 64, 0, stream>>>(W1, W2, W1p, W2p);
  k_deg_conv<<<2048, 256, 0, stream>>>(adj, Abf, dinv);
  k_layer1<<<512, 512, 0, stream>>>(Abf, x, W1p, b1, dinv, H1);
  k_layer2<<<512, 512, 0, stream>>>(Abf, H1, W2p, b2, dinv, pp);
  k_pool<<<256, 256, 0, stream>>>(pp, Wr, br, out);
}